// Round 12
// baseline (206.216 us; speedup 1.0000x reference)
//
#include <hip/hip_runtime.h>

#define N_NODES 100000
#define F1 128
#define NCLS 64
#define EPB 8      // edges per thread in edge-pass kernels
#define BCAP 12288 // bucketC LDS staging capacity (edges)

typedef __attribute__((ext_vector_type(8))) short bf16x8;
typedef __attribute__((ext_vector_type(4))) float f32x4;

__device__ __forceinline__ unsigned f2bf(float x) {
    unsigned u = __builtin_bit_cast(unsigned, x);
    u += 0x7fff + ((u >> 16) & 1);
    return u >> 16;
}
__device__ __forceinline__ float bflo(unsigned u) {
    return __builtin_bit_cast(float, u << 16);
}
__device__ __forceinline__ float bfhi(unsigned u) {
    return __builtin_bit_cast(float, u & 0xffff0000u);
}

// ds_swizzle helpers (offset BitMode: lane i reads ((i&and)|or)^xor, per 32-lane half)
#define SWZ_I(v, off) __builtin_amdgcn_ds_swizzle((v), (off))
#define SWZ_F(v, off) __builtin_bit_cast(float, __builtin_amdgcn_ds_swizzle(__builtin_bit_cast(int, (v)), (off)))

__device__ __forceinline__ int load_edge(const int* ei, int is64, long long idx) {
    return is64 ? ei[2 * idx] : ei[idx];
}

// Inline edge-dtype probe: wave 0 ballots on the first 64 odd int32 words.
#define EDGE_PROBE(ei, s_is64, tid) { \
    int v_ = (ei)[2 * ((tid) & 63) + 1]; \
    unsigned long long b_ = __ballot(v_ == 0); \
    if ((tid) == 0) s_is64 = (b_ == ~0ull) ? 1 : 0; }

// 256-wide LDS inclusive scan of bsum; exclusive prefix for chunk j is
// (j==0) ? 0 : sm[j-1].
#define BSUM_SCAN(sm, bsum, nb, tid) { \
    sm[tid] = ((tid) < (nb)) ? bsum[tid] : 0; \
    __syncthreads(); \
    for (int off_ = 1; off_ < 256; off_ <<= 1) { \
        int t_ = ((tid) >= off_) ? sm[(tid) - off_] : 0; \
        __syncthreads(); \
        sm[tid] += t_; \
        __syncthreads(); \
    } }

// ---------------------------------------------------------------------------
// FUSED: blocks [0,EB) = per-block LDS bucket histogram (bucket = dst>>9);
// blocks [EB, EB+nG1) = layer1 MFMA GEMM. Independent work, co-scheduled.
__global__ __launch_bounds__(256) void histgemm1_kernel(
        const int* __restrict__ ei, int* __restrict__ ghBM, int EB, int E,
        const float* __restrict__ x, const float* __restrict__ W,
        const float* __restrict__ att_s, const float* __restrict__ att_d,
        unsigned* __restrict__ hp, float* __restrict__ as_, float* __restrict__ ad_, int n) {
    __shared__ uint4 WtS[2048];                 // 32 KB (gemm); hist uses 1 KB
    __shared__ int s_is64;
    int tid = threadIdx.x;
    if (blockIdx.x < (unsigned)EB) {
        // ---------------- hist part ----------------
        int* bins = (int*)WtS;
        bins[tid] = 0;
        EDGE_PROBE(ei, s_is64, tid)
        __syncthreads();
        int is64 = s_is64;
        long long base = (long long)blockIdx.x * 2048 + tid * EPB;
        int d[EPB];
        #pragma unroll
        for (int k = 0; k < EPB; ++k) {
            long long e = base + k;
            d[k] = (e < E) ? load_edge(ei, is64, (long long)E + e) : -1;
        }
        #pragma unroll
        for (int k = 0; k < EPB; ++k)
            if (d[k] >= 0) atomicAdd(&bins[d[k] >> 9], 1);
        __syncthreads();
        ghBM[(size_t)tid * EB + blockIdx.x] = bins[tid];
        return;
    }
    // ---------------- gemm1 part ----------------
    unsigned* Wt = (unsigned*)WtS;
    {   // stage W^T (convert f32->bf16), swizzle bytecol ^= (ch&7)<<4
        int ch = tid & 127, fb = tid >> 7;
        #pragma unroll
        for (int j8 = 0; j8 < 8; ++j8) {
            int f0 = fb * 64 + j8 * 8;
            unsigned pk[4];
            #pragma unroll
            for (int p = 0; p < 4; ++p) {
                float lo = W[(size_t)(f0 + 2 * p) * 128 + ch];
                float hi = W[(size_t)(f0 + 2 * p + 1) * 128 + ch];
                pk[p] = f2bf(lo) | (f2bf(hi) << 16);
            }
            int bcol = (f0 * 2) ^ ((ch & 7) << 4);
            *(uint4*)&Wt[ch * 64 + (bcol >> 2)] = *(uint4*)pk;
        }
    }
    __syncthreads();
    int lane = tid & 63, w = tid >> 6;
    int col = lane & 15, quad = lane >> 4;
    int nodebase = (blockIdx.x - EB) * 128 + w * 32;
    bf16x8 a[2][4];
    #pragma unroll
    for (int s = 0; s < 2; ++s) {
        int node = nodebase + s * 16 + col;
        const float* xr = x + (size_t)node * 128;
        bool v = node < n;
        #pragma unroll
        for (int kk = 0; kk < 4; ++kk) {
            float4 lo = v ? *(const float4*)&xr[kk * 32 + quad * 8]
                          : make_float4(0.f, 0.f, 0.f, 0.f);
            float4 hi = v ? *(const float4*)&xr[kk * 32 + quad * 8 + 4]
                          : make_float4(0.f, 0.f, 0.f, 0.f);
            unsigned pk[4];
            pk[0] = f2bf(lo.x) | (f2bf(lo.y) << 16);
            pk[1] = f2bf(lo.z) | (f2bf(lo.w) << 16);
            pk[2] = f2bf(hi.x) | (f2bf(hi.y) << 16);
            pk[3] = f2bf(hi.z) | (f2bf(hi.w) << 16);
            a[s][kk] = *(bf16x8*)pk;
        }
    }
    f32x4 acc[2][8] = {};
    #pragma unroll
    for (int c = 0; c < 8; ++c) {
        int brow = c * 16 + col;
        bf16x8 b[4];
        #pragma unroll
        for (int kk = 0; kk < 4; ++kk) {
            int bcol = (kk * 64 + quad * 16) ^ ((brow & 7) << 4);
            b[kk] = *(bf16x8*)&Wt[brow * 64 + (bcol >> 2)];
        }
        #pragma unroll
        for (int s = 0; s < 2; ++s)
            #pragma unroll
            for (int kk = 0; kk < 4; ++kk)
                acc[s][c] = __builtin_amdgcn_mfma_f32_16x16x32_bf16(a[s][kk], b[kk], acc[s][c], 0, 0, 0);
    }
    float aS[8], aD[8];
    #pragma unroll
    for (int c = 0; c < 8; ++c) { aS[c] = att_s[c * 16 + col]; aD[c] = att_d[c * 16 + col]; }
    #pragma unroll
    for (int s = 0; s < 2; ++s) {
        #pragma unroll
        for (int c = 0; c < 8; ++c) {
            #pragma unroll
            for (int r = 0; r < 4; ++r) {
                float own = acc[s][c][r];
                float par = SWZ_F(own, 0x041F);        // lane ^ 1
                int node = nodebase + s * 16 + quad * 4 + r;
                if (!(lane & 1) && node < n)
                    hp[(size_t)node * 64 + c * 8 + (col >> 1)] =
                        f2bf(own) | (f2bf(par) << 16);
            }
        }
        #pragma unroll
        for (int h = 0; h < 4; ++h) {
            #pragma unroll
            for (int r = 0; r < 4; ++r) {
                float ps = acc[s][2 * h][r] * aS[2 * h] + acc[s][2 * h + 1][r] * aS[2 * h + 1];
                float pd = acc[s][2 * h][r] * aD[2 * h] + acc[s][2 * h + 1][r] * aD[2 * h + 1];
                ps += SWZ_F(ps, 0x041F); pd += SWZ_F(pd, 0x041F);
                ps += SWZ_F(ps, 0x081F); pd += SWZ_F(pd, 0x081F);
                ps += SWZ_F(ps, 0x101F); pd += SWZ_F(pd, 0x101F);
                ps += SWZ_F(ps, 0x201F); pd += SWZ_F(pd, 0x201F);
                int node = nodebase + s * 16 + quad * 4 + r;
                if (col == 0 && node < n) {
                    as_[(size_t)node * 4 + h] = ps;
                    ad_[(size_t)node * 4 + h] = pd;
                }
            }
        }
    }
}

// pscanA: block-local exclusive scan over ghBM (length K), bsum[blk] = total.
#define SCAN_BLOCK 1024
__global__ void pscanA_kernel(int* __restrict__ g, int* __restrict__ bsum, int K) {
    __shared__ int sm[SCAN_BLOCK];
    int tid = threadIdx.x;
    int i = blockIdx.x * SCAN_BLOCK + tid;
    int v = (i < K) ? g[i] : 0;
    sm[tid] = v;
    __syncthreads();
    for (int off = 1; off < SCAN_BLOCK; off <<= 1) {
        int t = (tid >= off) ? sm[tid - off] : 0;
        __syncthreads();
        sm[tid] += t;
        __syncthreads();
    }
    if (i < K) g[i] = sm[tid] - v;
    if (tid == SCAN_BLOCK - 1) bsum[blockIdx.x] = sm[tid];
}

// scatterB: finalize scan locally (bsum LDS scan), bucket-partition edges via
// LDS rank, packed write. Zero global atomics.
__global__ __launch_bounds__(256) void scatterB_kernel(
        const int* __restrict__ ei, const int* __restrict__ ghBM, int EB,
        const int* __restrict__ bsum, int nbK,
        unsigned* __restrict__ tmp, int E) {
    __shared__ int base[256];
    __shared__ int sm[256];
    __shared__ int s_is64;
    int tid = threadIdx.x;
    EDGE_PROBE(ei, s_is64, tid)
    BSUM_SCAN(sm, bsum, nbK, tid)
    {
        int idx = tid * EB + blockIdx.x;
        int chunk = idx >> 10;
        int pre = (chunk == 0) ? 0 : sm[chunk - 1];
        base[tid] = ghBM[(size_t)idx] + pre;
    }
    __syncthreads();
    int is64 = s_is64;
    long long eb = (long long)blockIdx.x * 2048 + tid * EPB;
    int d[EPB], s[EPB];
    #pragma unroll
    for (int k = 0; k < EPB; ++k) {
        long long e = eb + k;
        d[k] = (e < E) ? load_edge(ei, is64, (long long)E + e) : -1;
    }
    #pragma unroll
    for (int k = 0; k < EPB; ++k) {
        long long e = eb + k;
        s[k] = (e < E) ? load_edge(ei, is64, e) : 0;
    }
    #pragma unroll
    for (int k = 0; k < EPB; ++k) {
        if (d[k] >= 0) {
            int pos = atomicAdd(&base[d[k] >> 9], 1);
            tmp[pos] = (unsigned)s[k] | ((unsigned)(d[k] & 511) << 17);
        }
    }
}

// bucketC: one block per bucket; LDS-staged single pass (fallback: global
// 2-pass). LDS count over 512 local nodes -> scan -> row_ptr + ranked col.
__global__ __launch_bounds__(256) void bucketC_kernel(
        const unsigned* __restrict__ tmp, const int* __restrict__ ghBM, int EB,
        const int* __restrict__ bsum, int nbK,
        int* __restrict__ row_ptr, int* __restrict__ col, int E, int n) {
    __shared__ unsigned stmp[BCAP];
    __shared__ int lb[512];
    __shared__ int lo[512];
    __shared__ int sm[256];
    int bk = blockIdx.x;
    int tid = threadIdx.x;
    BSUM_SCAN(sm, bsum, nbK, tid)
    int i0 = bk * EB;
    int c0 = (i0 >> 10), p0 = (c0 == 0) ? 0 : sm[c0 - 1];
    int gbase = ghBM[(size_t)i0] + p0;
    int gend = E;
    if (bk < 255) {
        int i1 = (bk + 1) * EB;
        int c1 = (i1 >> 10), p1 = (c1 == 0) ? 0 : sm[c1 - 1];
        gend = ghBM[(size_t)i1] + p1;
    }
    int cnt = gend - gbase;
    bool lds = (cnt <= BCAP);
    __syncthreads();      // sm reuse barrier before lb init below
    lb[tid] = 0; lb[tid + 256] = 0;
    if (lds) {
        for (int i = tid; i < cnt; i += 256) stmp[i] = tmp[gbase + i];
    }
    __syncthreads();
    if (lds) {
        for (int i = tid; i < cnt; i += 256)
            atomicAdd(&lb[stmp[i] >> 17], 1);
    } else {
        for (int i = tid; i < cnt; i += 256)
            atomicAdd(&lb[tmp[gbase + i] >> 17], 1);
    }
    __syncthreads();
    int p = lb[2 * tid], q = lb[2 * tid + 1];
    int ps = p + q;
    sm[tid] = ps;
    __syncthreads();
    for (int off = 1; off < 256; off <<= 1) {
        int t = (tid >= off) ? sm[tid - off] : 0;
        __syncthreads();
        sm[tid] += t;
        __syncthreads();
    }
    int excl = sm[tid] - ps;
    int e0 = excl, e1 = excl + p;
    lo[2 * tid] = e0; lo[2 * tid + 1] = e1;
    int v0 = bk * 512 + 2 * tid;
    if (v0 <= n) row_ptr[v0] = gbase + e0;
    if (v0 + 1 <= n) row_ptr[v0 + 1] = gbase + e1;
    __syncthreads();
    if (lds) {
        for (int i = tid; i < cnt; i += 256) {
            unsigned v = stmp[i];
            int r = atomicAdd(&lo[v >> 17], 1);
            col[gbase + r] = (int)(v & 0x1FFFFu);
        }
    } else {
        for (int i = tid; i < cnt; i += 256) {
            unsigned v = tmp[gbase + i];
            int r = atomicAdd(&lo[v >> 17], 1);
            col[gbase + r] = (int)(v & 0x1FFFFu);
        }
    }
}

// ---------------------------------------------------------------------------
// Layer2 GEMM via MFMA bf16: [N,128(bf16-packed)]x[128,64].
__global__ __launch_bounds__(256) void gemm2_kernel(
        const unsigned* __restrict__ xp, const float* __restrict__ W,
        const float* __restrict__ att_s, const float* __restrict__ att_d,
        unsigned* __restrict__ hp, float* __restrict__ as_, float* __restrict__ ad_, int n) {
    __shared__ uint4 WtS[1024];                 // 16 KB: Wt[64ch][128k] bf16
    unsigned* Wt = (unsigned*)WtS;
    int tid = threadIdx.x;
    {   // stage W2^T
        int ch = tid & 63, fb = tid >> 6;
        #pragma unroll
        for (int j8 = 0; j8 < 4; ++j8) {
            int f0 = fb * 32 + j8 * 8;
            unsigned pk[4];
            #pragma unroll
            for (int p = 0; p < 4; ++p) {
                float lo = W[(size_t)(f0 + 2 * p) * 64 + ch];
                float hi = W[(size_t)(f0 + 2 * p + 1) * 64 + ch];
                pk[p] = f2bf(lo) | (f2bf(hi) << 16);
            }
            int bcol = (f0 * 2) ^ ((ch & 7) << 4);
            *(uint4*)&Wt[ch * 64 + (bcol >> 2)] = *(uint4*)pk;
        }
    }
    __syncthreads();
    int lane = tid & 63, w = tid >> 6;
    int col = lane & 15, quad = lane >> 4;
    int nodebase = blockIdx.x * 128 + w * 32;
    bf16x8 a[2][4];
    #pragma unroll
    for (int s = 0; s < 2; ++s) {
        int node = nodebase + s * 16 + col;
        bool v = node < n;
        #pragma unroll
        for (int kk = 0; kk < 4; ++kk) {
            uint4 u = v ? *(const uint4*)&xp[(size_t)node * 64 + kk * 16 + quad * 4]
                        : make_uint4(0, 0, 0, 0);
            a[s][kk] = *(bf16x8*)&u;
        }
    }
    f32x4 acc[2][4] = {};
    #pragma unroll
    for (int c = 0; c < 4; ++c) {
        int brow = c * 16 + col;
        bf16x8 b[4];
        #pragma unroll
        for (int kk = 0; kk < 4; ++kk) {
            int bcol = (kk * 64 + quad * 16) ^ ((brow & 7) << 4);
            b[kk] = *(bf16x8*)&Wt[brow * 64 + (bcol >> 2)];
        }
        #pragma unroll
        for (int s = 0; s < 2; ++s)
            #pragma unroll
            for (int kk = 0; kk < 4; ++kk)
                acc[s][c] = __builtin_amdgcn_mfma_f32_16x16x32_bf16(a[s][kk], b[kk], acc[s][c], 0, 0, 0);
    }
    float aS[4], aD[4];
    #pragma unroll
    for (int c = 0; c < 4; ++c) { aS[c] = att_s[c * 16 + col]; aD[c] = att_d[c * 16 + col]; }
    #pragma unroll
    for (int s = 0; s < 2; ++s) {
        #pragma unroll
        for (int c = 0; c < 4; ++c) {
            #pragma unroll
            for (int r = 0; r < 4; ++r) {
                float own = acc[s][c][r];
                float par = SWZ_F(own, 0x041F);
                int node = nodebase + s * 16 + quad * 4 + r;
                if (!(lane & 1) && node < n)
                    hp[(size_t)node * 32 + c * 8 + (col >> 1)] =
                        f2bf(own) | (f2bf(par) << 16);
            }
        }
        #pragma unroll
        for (int r = 0; r < 4; ++r) {
            float ps = 0.f, pd = 0.f;
            #pragma unroll
            for (int c = 0; c < 4; ++c) {
                ps = fmaf(acc[s][c][r], aS[c], ps);
                pd = fmaf(acc[s][c][r], aD[c], pd);
            }
            ps += SWZ_F(ps, 0x041F); pd += SWZ_F(pd, 0x041F);
            ps += SWZ_F(ps, 0x081F); pd += SWZ_F(pd, 0x081F);
            ps += SWZ_F(ps, 0x101F); pd += SWZ_F(pd, 0x101F);
            ps += SWZ_F(ps, 0x201F); pd += SWZ_F(pd, 0x201F);
            int node = nodebase + s * 16 + quad * 4 + r;
            if (col == 0 && node < n) { as_[node] = ps; ad_[node] = pd; }
        }
    }
}

// ---------------------------------------------------------------------------
// Aggregation layer1 (wide-gather): wave per dst node; HALF-wave per edge
// (2 edges/step). Lane (h = l>>5, c = l&31) reads uint2 = channels 4c..4c+3
// of edge (2k+h). Weights amortized 1 exp / 16 edges via specialist lanes
// (edge&15 | head<<4), consumer shfl index (2k+h)|(headc<<4).
#define A1N_SUB(B) { \
    int sspec = __shfl(myc, (B) + (lane & 15)); \
    float ee_ = as_[(size_t)sspec * 4 + heads] + adv_s; \
    ee_ = fmaxf(ee_, 0.2f * ee_); \
    float ew = ((cb + (B) + (lane & 15)) < end) ? __expf(ee_) : 0.f; \
    int s0 = __shfl(myc, (B) + 0 + h); \
    int s1 = __shfl(myc, (B) + 2 + h); \
    int s2 = __shfl(myc, (B) + 4 + h); \
    int s3 = __shfl(myc, (B) + 6 + h); \
    int s4 = __shfl(myc, (B) + 8 + h); \
    int s5 = __shfl(myc, (B) + 10 + h); \
    int s6 = __shfl(myc, (B) + 12 + h); \
    int s7 = __shfl(myc, (B) + 14 + h); \
    uint2 v0 = *(const uint2*)&hp[(size_t)s0 * 64 + c * 2]; \
    uint2 v1 = *(const uint2*)&hp[(size_t)s1 * 64 + c * 2]; \
    uint2 v2 = *(const uint2*)&hp[(size_t)s2 * 64 + c * 2]; \
    uint2 v3 = *(const uint2*)&hp[(size_t)s3 * 64 + c * 2]; \
    uint2 v4 = *(const uint2*)&hp[(size_t)s4 * 64 + c * 2]; \
    uint2 v5 = *(const uint2*)&hp[(size_t)s5 * 64 + c * 2]; \
    uint2 v6 = *(const uint2*)&hp[(size_t)s6 * 64 + c * 2]; \
    uint2 v7 = *(const uint2*)&hp[(size_t)s7 * 64 + c * 2]; \
    float q0 = __shfl(ew, wbase + 0); \
    float q1 = __shfl(ew, wbase + 2); \
    float q2 = __shfl(ew, wbase + 4); \
    float q3 = __shfl(ew, wbase + 6); \
    float q4 = __shfl(ew, wbase + 8); \
    float q5 = __shfl(ew, wbase + 10); \
    float q6 = __shfl(ew, wbase + 12); \
    float q7 = __shfl(ew, wbase + 14); \
    s += q0; a0 = fmaf(q0, bflo(v0.x), a0); a1 = fmaf(q0, bfhi(v0.x), a1); \
             a2 = fmaf(q0, bflo(v0.y), a2); a3 = fmaf(q0, bfhi(v0.y), a3); \
    s += q1; a0 = fmaf(q1, bflo(v1.x), a0); a1 = fmaf(q1, bfhi(v1.x), a1); \
             a2 = fmaf(q1, bflo(v1.y), a2); a3 = fmaf(q1, bfhi(v1.y), a3); \
    s += q2; a0 = fmaf(q2, bflo(v2.x), a0); a1 = fmaf(q2, bfhi(v2.x), a1); \
             a2 = fmaf(q2, bflo(v2.y), a2); a3 = fmaf(q2, bfhi(v2.y), a3); \
    s += q3; a0 = fmaf(q3, bflo(v3.x), a0); a1 = fmaf(q3, bfhi(v3.x), a1); \
             a2 = fmaf(q3, bflo(v3.y), a2); a3 = fmaf(q3, bfhi(v3.y), a3); \
    s += q4; a0 = fmaf(q4, bflo(v4.x), a0); a1 = fmaf(q4, bfhi(v4.x), a1); \
             a2 = fmaf(q4, bflo(v4.y), a2); a3 = fmaf(q4, bfhi(v4.y), a3); \
    s += q5; a0 = fmaf(q5, bflo(v5.x), a0); a1 = fmaf(q5, bfhi(v5.x), a1); \
             a2 = fmaf(q5, bflo(v5.y), a2); a3 = fmaf(q5, bfhi(v5.y), a3); \
    s += q6; a0 = fmaf(q6, bflo(v6.x), a0); a1 = fmaf(q6, bfhi(v6.x), a1); \
             a2 = fmaf(q6, bflo(v6.y), a2); a3 = fmaf(q6, bfhi(v6.y), a3); \
    s += q7; a0 = fmaf(q7, bflo(v7.x), a0); a1 = fmaf(q7, bfhi(v7.x), a1); \
             a2 = fmaf(q7, bflo(v7.y), a2); a3 = fmaf(q7, bfhi(v7.y), a3); }

__global__ __launch_bounds__(256) void agg1_kernel(
        const unsigned* __restrict__ hp, const float* __restrict__ as_,
        const float* __restrict__ ad_, const int* __restrict__ row_ptr,
        const int* __restrict__ col, const float* __restrict__ bias,
        unsigned* __restrict__ outp, int n) {
    int wid = (blockIdx.x * 256 + threadIdx.x) >> 6;
    int lane = threadIdx.x & 63;
    if (wid >= n) return;
    int node = wid;
    int h = lane >> 5;                  // edge parity (half)
    int c = lane & 31;                  // channels 4c..4c+3
    int headc = c >> 3;                 // consumer head
    int heads = lane >> 4;              // specialist head
    int wbase = h + (headc << 4);       // weight shfl base (+2k per step)
    float adv_c = ad_[(size_t)node * 4 + headc];
    float adv_s = ad_[(size_t)node * 4 + heads];
    float s, a0, a1, a2, a3;
    {   // self loop (counted in half 0 only)
        float e0 = as_[(size_t)node * 4 + headc] + adv_c;
        e0 = fmaxf(e0, 0.2f * e0);
        float w0 = (h == 0) ? __expf(e0) : 0.f;
        uint2 u = *(const uint2*)&hp[(size_t)node * 64 + c * 2];
        s = w0;
        a0 = w0 * bflo(u.x); a1 = w0 * bfhi(u.x);
        a2 = w0 * bflo(u.y); a3 = w0 * bfhi(u.y);
    }
    int beg = row_ptr[node], end = row_ptr[node + 1];
    for (int cb = beg; cb < end; cb += 32) {
        int m = end - cb; if (m > 32) m = 32;
        int ci = cb + c;
        int myc = col[(ci < end) ? ci : (end - 1)];   // mirrored into halves
        A1N_SUB(0)
        if (m > 16) A1N_SUB(16)
    }
    s  += __shfl_xor(s, 32);
    a0 += __shfl_xor(a0, 32); a1 += __shfl_xor(a1, 32);
    a2 += __shfl_xor(a2, 32); a3 += __shfl_xor(a3, 32);
    if (h == 0) {
        float inv = 1.0f / (s + 1e-16f);
        float4 b = *(const float4*)&bias[c * 4];
        uint2 o;
        o.x = f2bf(a0 * inv + b.x) | (f2bf(a1 * inv + b.y) << 16);
        o.y = f2bf(a2 * inv + b.z) | (f2bf(a3 * inv + b.w) << 16);
        *(uint2*)&outp[(size_t)node * 64 + c * 2] = o;
    }
}

// ---------------------------------------------------------------------------
// Aggregation layer2 (wide-gather): wave per dst node; QUARTER-wave per edge
// (4 edges/step). Lane (g = l>>4, w16 = l&15) reads uint2 = channels
// 4w16..4w16+3 of edge (4k+g). 64-edge col window, 1 exp per lane per window.
#define A2N_G4(K0) { \
    int i0 = 4 * (K0) + g; \
    int s0 = __shfl(myc, i0); \
    int s1 = __shfl(myc, i0 + 4); \
    int s2 = __shfl(myc, i0 + 8); \
    int s3 = __shfl(myc, i0 + 12); \
    uint2 v0 = *(const uint2*)&hp[(size_t)s0 * 32 + w16 * 2]; \
    uint2 v1 = *(const uint2*)&hp[(size_t)s1 * 32 + w16 * 2]; \
    uint2 v2 = *(const uint2*)&hp[(size_t)s2 * 32 + w16 * 2]; \
    uint2 v3 = *(const uint2*)&hp[(size_t)s3 * 32 + w16 * 2]; \
    float q0 = __shfl(ewl, i0); \
    float q1 = __shfl(ewl, i0 + 4); \
    float q2 = __shfl(ewl, i0 + 8); \
    float q3 = __shfl(ewl, i0 + 12); \
    s += q0; a0 = fmaf(q0, bflo(v0.x), a0); a1 = fmaf(q0, bfhi(v0.x), a1); \
             a2 = fmaf(q0, bflo(v0.y), a2); a3 = fmaf(q0, bfhi(v0.y), a3); \
    s += q1; a0 = fmaf(q1, bflo(v1.x), a0); a1 = fmaf(q1, bfhi(v1.x), a1); \
             a2 = fmaf(q1, bflo(v1.y), a2); a3 = fmaf(q1, bfhi(v1.y), a3); \
    s += q2; a0 = fmaf(q2, bflo(v2.x), a0); a1 = fmaf(q2, bfhi(v2.x), a1); \
             a2 = fmaf(q2, bflo(v2.y), a2); a3 = fmaf(q2, bfhi(v2.y), a3); \
    s += q3; a0 = fmaf(q3, bflo(v3.x), a0); a1 = fmaf(q3, bfhi(v3.x), a1); \
             a2 = fmaf(q3, bflo(v3.y), a2); a3 = fmaf(q3, bfhi(v3.y), a3); }

__global__ __launch_bounds__(256) void agg2_kernel(
        const unsigned* __restrict__ hp, const float* __restrict__ as_,
        const float* __restrict__ ad_, const int* __restrict__ row_ptr,
        const int* __restrict__ col, const float* __restrict__ bias,
        float* __restrict__ out, int n) {
    int wid = (blockIdx.x * 256 + threadIdx.x) >> 6;
    int lane = threadIdx.x & 63;
    if (wid >= n) return;
    int node = wid;
    int g = lane >> 4;                  // edge group 0..3
    int w16 = lane & 15;                // channels 4w16..4w16+3
    float adv = ad_[node];
    float s, a0, a1, a2, a3;
    {   // self loop (group 0 only)
        float e = as_[node] + adv; e = fmaxf(e, 0.2f * e);
        float w = (g == 0) ? __expf(e) : 0.f;
        uint2 u = *(const uint2*)&hp[(size_t)node * 32 + w16 * 2];
        s = w;
        a0 = w * bflo(u.x); a1 = w * bfhi(u.x);
        a2 = w * bflo(u.y); a3 = w * bfhi(u.y);
    }
    int beg = row_ptr[node], end = row_ptr[node + 1];
    for (int cb = beg; cb < end; cb += 64) {
        int m = end - cb; if (m > 64) m = 64;
        int ci = cb + lane;
        int myc = col[(ci < end) ? ci : (end - 1)];
        float ee = as_[myc] + adv; ee = fmaxf(ee, 0.2f * ee);
        float ewl = (ci < end) ? __expf(ee) : 0.f;
        A2N_G4(0)
        if (m > 16) A2N_G4(4)
        if (m > 32) A2N_G4(8)
        if (m > 48) A2N_G4(12)
    }
    s  += __shfl_xor(s, 16);  s  += __shfl_xor(s, 32);
    a0 += __shfl_xor(a0, 16); a0 += __shfl_xor(a0, 32);
    a1 += __shfl_xor(a1, 16); a1 += __shfl_xor(a1, 32);
    a2 += __shfl_xor(a2, 16); a2 += __shfl_xor(a2, 32);
    a3 += __shfl_xor(a3, 16); a3 += __shfl_xor(a3, 32);
    if (lane < 16) {
        float inv = 1.0f / (s + 1e-16f);
        float4 b = *(const float4*)&bias[w16 * 4];
        *(float4*)&out[(size_t)node * 64 + w16 * 4] =
            make_float4(a0 * inv + b.x, a1 * inv + b.y,
                        a2 * inv + b.z, a3 * inv + b.w);
    }
}

// ---------------------------------------------------------------------------
extern "C" void kernel_launch(void* const* d_in, const int* in_sizes, int n_in,
                              void* d_out, int out_size, void* d_ws, size_t ws_size,
                              hipStream_t stream) {
    const float* inp   = (const float*)d_in[0];
    const int*   ei    = (const int*)d_in[1];
    const float* W1    = (const float*)d_in[2];
    const float* atts1 = (const float*)d_in[3];
    const float* attd1 = (const float*)d_in[4];
    const float* bias1 = (const float*)d_in[5];
    const float* W2    = (const float*)d_in[6];
    const float* atts2 = (const float*)d_in[7];
    const float* attd2 = (const float*)d_in[8];
    const float* bias2 = (const float*)d_in[9];
    float* out = (float*)d_out;

    const int N = N_NODES;
    const int E = in_sizes[1] / 2;

    const int EB = (E + 2047) / 2048;          // edge blocks
    const int K = 256 * EB;                    // ghBM length
    const int nbK = (K + SCAN_BLOCK - 1) / SCAN_BLOCK;   // <=256 for E<=2M
    const int nG1 = (N + 127) / 128;           // gemm1 blocks

    unsigned* h1p = (unsigned*)d_ws;               // N*64 uints (layer2 reuses N*32)
    unsigned* x1p = h1p + (size_t)N * 64;          // N*64 uints (bf16-packed x1)
    float* as1 = (float*)(x1p + (size_t)N * 64);   // N*4
    float* ad1 = as1 + (size_t)N * 4;              // N*4
    int* row_ptr  = (int*)(ad1 + (size_t)N * 4);   // N+1
    int* col      = row_ptr + N + 1;               // E
    int* ghBM     = col + E;                       // 256*EB
    int* bsum     = ghBM + K;                      // 256
    unsigned* tmp = x1p;                           // E uints, aliases x1p (dead until agg1)

    // CSR build (hist fused with layer1 GEMM; scan finalized in consumers)
    histgemm1_kernel<<<EB + nG1, 256, 0, stream>>>(
        ei, ghBM, EB, E, inp, W1, atts1, attd1, h1p, as1, ad1, N);
    pscanA_kernel<<<nbK, SCAN_BLOCK, 0, stream>>>(ghBM, bsum, K);
    scatterB_kernel<<<EB, 256, 0, stream>>>(ei, ghBM, EB, bsum, nbK, tmp, E);
    bucketC_kernel<<<256, 256, 0, stream>>>(tmp, ghBM, EB, bsum, nbK, row_ptr, col, E, N);

    agg1_kernel<<<(N + 3) / 4, 256, 0, stream>>>(h1p, as1, ad1, row_ptr, col, bias1, x1p, N);

    // layer 2 (h2p aliases h1p; as2/ad2 alias as1/ad1)
    gemm2_kernel<<<(N + 127) / 128, 256, 0, stream>>>(x1p, W2, atts2, attd2, h1p, as1, ad1, N);
    agg2_kernel<<<(N + 3) / 4, 256, 0, stream>>>(h1p, as1, ad1, row_ptr, col, bias2, out, N);
}

// Round 13
// 204.461 us; speedup vs baseline: 1.0086x; 1.0086x over previous
//
#include <hip/hip_runtime.h>

#define N_NODES 100000
#define F1 128
#define NCLS 64
#define EPB 8      // edges per thread in edge-pass kernels
#define BCAP 12288 // bucketC LDS staging capacity (edges)

typedef __attribute__((ext_vector_type(8))) short bf16x8;
typedef __attribute__((ext_vector_type(4))) float f32x4;

__device__ __forceinline__ unsigned f2bf(float x) {
    unsigned u = __builtin_bit_cast(unsigned, x);
    u += 0x7fff + ((u >> 16) & 1);
    return u >> 16;
}
__device__ __forceinline__ float bflo(unsigned u) {
    return __builtin_bit_cast(float, u << 16);
}
__device__ __forceinline__ float bfhi(unsigned u) {
    return __builtin_bit_cast(float, u & 0xffff0000u);
}

// ds_swizzle helpers (offset BitMode: lane i reads ((i&and)|or)^xor, per 32-lane half)
#define SWZ_I(v, off) __builtin_amdgcn_ds_swizzle((v), (off))
#define SWZ_F(v, off) __builtin_bit_cast(float, __builtin_amdgcn_ds_swizzle(__builtin_bit_cast(int, (v)), (off)))

__device__ __forceinline__ int load_edge(const int* ei, int is64, long long idx) {
    return is64 ? ei[2 * idx] : ei[idx];
}

// Inline edge-dtype probe: wave 0 ballots on the first 64 odd int32 words.
#define EDGE_PROBE(ei, s_is64, tid) { \
    int v_ = (ei)[2 * ((tid) & 63) + 1]; \
    unsigned long long b_ = __ballot(v_ == 0); \
    if ((tid) == 0) s_is64 = (b_ == ~0ull) ? 1 : 0; }

// 256-wide LDS inclusive scan of bsum; exclusive prefix for chunk j is
// (j==0) ? 0 : sm[j-1].
#define BSUM_SCAN(sm, bsum, nb, tid) { \
    sm[tid] = ((tid) < (nb)) ? bsum[tid] : 0; \
    __syncthreads(); \
    for (int off_ = 1; off_ < 256; off_ <<= 1) { \
        int t_ = ((tid) >= off_) ? sm[(tid) - off_] : 0; \
        __syncthreads(); \
        sm[tid] += t_; \
        __syncthreads(); \
    } }

// ---------------------------------------------------------------------------
// FUSED: blocks [0,EB) = per-block LDS bucket histogram (bucket = dst>>9);
// blocks [EB, EB+nG1) = layer1 MFMA GEMM. Independent work, co-scheduled.
__global__ __launch_bounds__(256) void histgemm1_kernel(
        const int* __restrict__ ei, int* __restrict__ ghBM, int EB, int E,
        const float* __restrict__ x, const float* __restrict__ W,
        const float* __restrict__ att_s, const float* __restrict__ att_d,
        unsigned* __restrict__ hp, float* __restrict__ as_, float* __restrict__ ad_, int n) {
    __shared__ uint4 WtS[2048];                 // 32 KB (gemm); hist uses 1 KB
    __shared__ int s_is64;
    int tid = threadIdx.x;
    if (blockIdx.x < (unsigned)EB) {
        // ---------------- hist part ----------------
        int* bins = (int*)WtS;
        bins[tid] = 0;
        EDGE_PROBE(ei, s_is64, tid)
        __syncthreads();
        int is64 = s_is64;
        long long base = (long long)blockIdx.x * 2048 + tid * EPB;
        int d[EPB];
        #pragma unroll
        for (int k = 0; k < EPB; ++k) {
            long long e = base + k;
            d[k] = (e < E) ? load_edge(ei, is64, (long long)E + e) : -1;
        }
        #pragma unroll
        for (int k = 0; k < EPB; ++k)
            if (d[k] >= 0) atomicAdd(&bins[d[k] >> 9], 1);
        __syncthreads();
        ghBM[(size_t)tid * EB + blockIdx.x] = bins[tid];
        return;
    }
    // ---------------- gemm1 part ----------------
    unsigned* Wt = (unsigned*)WtS;
    {   // stage W^T (convert f32->bf16), swizzle bytecol ^= (ch&7)<<4
        int ch = tid & 127, fb = tid >> 7;
        #pragma unroll
        for (int j8 = 0; j8 < 8; ++j8) {
            int f0 = fb * 64 + j8 * 8;
            unsigned pk[4];
            #pragma unroll
            for (int p = 0; p < 4; ++p) {
                float lo = W[(size_t)(f0 + 2 * p) * 128 + ch];
                float hi = W[(size_t)(f0 + 2 * p + 1) * 128 + ch];
                pk[p] = f2bf(lo) | (f2bf(hi) << 16);
            }
            int bcol = (f0 * 2) ^ ((ch & 7) << 4);
            *(uint4*)&Wt[ch * 64 + (bcol >> 2)] = *(uint4*)pk;
        }
    }
    __syncthreads();
    int lane = tid & 63, w = tid >> 6;
    int col = lane & 15, quad = lane >> 4;
    int nodebase = (blockIdx.x - EB) * 128 + w * 32;
    bf16x8 a[2][4];
    #pragma unroll
    for (int s = 0; s < 2; ++s) {
        int node = nodebase + s * 16 + col;
        const float* xr = x + (size_t)node * 128;
        bool v = node < n;
        #pragma unroll
        for (int kk = 0; kk < 4; ++kk) {
            float4 lo = v ? *(const float4*)&xr[kk * 32 + quad * 8]
                          : make_float4(0.f, 0.f, 0.f, 0.f);
            float4 hi = v ? *(const float4*)&xr[kk * 32 + quad * 8 + 4]
                          : make_float4(0.f, 0.f, 0.f, 0.f);
            unsigned pk[4];
            pk[0] = f2bf(lo.x) | (f2bf(lo.y) << 16);
            pk[1] = f2bf(lo.z) | (f2bf(lo.w) << 16);
            pk[2] = f2bf(hi.x) | (f2bf(hi.y) << 16);
            pk[3] = f2bf(hi.z) | (f2bf(hi.w) << 16);
            a[s][kk] = *(bf16x8*)pk;
        }
    }
    f32x4 acc[2][8] = {};
    #pragma unroll
    for (int c = 0; c < 8; ++c) {
        int brow = c * 16 + col;
        bf16x8 b[4];
        #pragma unroll
        for (int kk = 0; kk < 4; ++kk) {
            int bcol = (kk * 64 + quad * 16) ^ ((brow & 7) << 4);
            b[kk] = *(bf16x8*)&Wt[brow * 64 + (bcol >> 2)];
        }
        #pragma unroll
        for (int s = 0; s < 2; ++s)
            #pragma unroll
            for (int kk = 0; kk < 4; ++kk)
                acc[s][c] = __builtin_amdgcn_mfma_f32_16x16x32_bf16(a[s][kk], b[kk], acc[s][c], 0, 0, 0);
    }
    float aS[8], aD[8];
    #pragma unroll
    for (int c = 0; c < 8; ++c) { aS[c] = att_s[c * 16 + col]; aD[c] = att_d[c * 16 + col]; }
    #pragma unroll
    for (int s = 0; s < 2; ++s) {
        #pragma unroll
        for (int c = 0; c < 8; ++c) {
            #pragma unroll
            for (int r = 0; r < 4; ++r) {
                float own = acc[s][c][r];
                float par = SWZ_F(own, 0x041F);        // lane ^ 1
                int node = nodebase + s * 16 + quad * 4 + r;
                if (!(lane & 1) && node < n)
                    hp[(size_t)node * 64 + c * 8 + (col >> 1)] =
                        f2bf(own) | (f2bf(par) << 16);
            }
        }
        #pragma unroll
        for (int h = 0; h < 4; ++h) {
            #pragma unroll
            for (int r = 0; r < 4; ++r) {
                float ps = acc[s][2 * h][r] * aS[2 * h] + acc[s][2 * h + 1][r] * aS[2 * h + 1];
                float pd = acc[s][2 * h][r] * aD[2 * h] + acc[s][2 * h + 1][r] * aD[2 * h + 1];
                ps += SWZ_F(ps, 0x041F); pd += SWZ_F(pd, 0x041F);
                ps += SWZ_F(ps, 0x081F); pd += SWZ_F(pd, 0x081F);
                ps += SWZ_F(ps, 0x101F); pd += SWZ_F(pd, 0x101F);
                ps += SWZ_F(ps, 0x201F); pd += SWZ_F(pd, 0x201F);
                int node = nodebase + s * 16 + quad * 4 + r;
                if (col == 0 && node < n) {
                    as_[(size_t)node * 4 + h] = ps;
                    ad_[(size_t)node * 4 + h] = pd;
                }
            }
        }
    }
}

// pscanA: block-local exclusive scan over ghBM (length K), bsum[blk] = total.
#define SCAN_BLOCK 1024
__global__ void pscanA_kernel(int* __restrict__ g, int* __restrict__ bsum, int K) {
    __shared__ int sm[SCAN_BLOCK];
    int tid = threadIdx.x;
    int i = blockIdx.x * SCAN_BLOCK + tid;
    int v = (i < K) ? g[i] : 0;
    sm[tid] = v;
    __syncthreads();
    for (int off = 1; off < SCAN_BLOCK; off <<= 1) {
        int t = (tid >= off) ? sm[tid - off] : 0;
        __syncthreads();
        sm[tid] += t;
        __syncthreads();
    }
    if (i < K) g[i] = sm[tid] - v;
    if (tid == SCAN_BLOCK - 1) bsum[blockIdx.x] = sm[tid];
}

// scatterB: finalize scan locally (bsum LDS scan), bucket-partition edges via
// LDS rank, packed write. Zero global atomics.
__global__ __launch_bounds__(256) void scatterB_kernel(
        const int* __restrict__ ei, const int* __restrict__ ghBM, int EB,
        const int* __restrict__ bsum, int nbK,
        unsigned* __restrict__ tmp, int E) {
    __shared__ int base[256];
    __shared__ int sm[256];
    __shared__ int s_is64;
    int tid = threadIdx.x;
    EDGE_PROBE(ei, s_is64, tid)
    BSUM_SCAN(sm, bsum, nbK, tid)
    {
        int idx = tid * EB + blockIdx.x;
        int chunk = idx >> 10;
        int pre = (chunk == 0) ? 0 : sm[chunk - 1];
        base[tid] = ghBM[(size_t)idx] + pre;
    }
    __syncthreads();
    int is64 = s_is64;
    long long eb = (long long)blockIdx.x * 2048 + tid * EPB;
    int d[EPB], s[EPB];
    #pragma unroll
    for (int k = 0; k < EPB; ++k) {
        long long e = eb + k;
        d[k] = (e < E) ? load_edge(ei, is64, (long long)E + e) : -1;
    }
    #pragma unroll
    for (int k = 0; k < EPB; ++k) {
        long long e = eb + k;
        s[k] = (e < E) ? load_edge(ei, is64, e) : 0;
    }
    #pragma unroll
    for (int k = 0; k < EPB; ++k) {
        if (d[k] >= 0) {
            int pos = atomicAdd(&base[d[k] >> 9], 1);
            tmp[pos] = (unsigned)s[k] | ((unsigned)(d[k] & 511) << 17);
        }
    }
}

// bucketC: one block per bucket; LDS-staged single pass (fallback: global
// 2-pass). LDS count over 512 local nodes -> scan -> row_ptr + ranked col.
__global__ __launch_bounds__(256) void bucketC_kernel(
        const unsigned* __restrict__ tmp, const int* __restrict__ ghBM, int EB,
        const int* __restrict__ bsum, int nbK,
        int* __restrict__ row_ptr, int* __restrict__ col, int E, int n) {
    __shared__ unsigned stmp[BCAP];
    __shared__ int lb[512];
    __shared__ int lo[512];
    __shared__ int sm[256];
    int bk = blockIdx.x;
    int tid = threadIdx.x;
    BSUM_SCAN(sm, bsum, nbK, tid)
    int i0 = bk * EB;
    int c0 = (i0 >> 10), p0 = (c0 == 0) ? 0 : sm[c0 - 1];
    int gbase = ghBM[(size_t)i0] + p0;
    int gend = E;
    if (bk < 255) {
        int i1 = (bk + 1) * EB;
        int c1 = (i1 >> 10), p1 = (c1 == 0) ? 0 : sm[c1 - 1];
        gend = ghBM[(size_t)i1] + p1;
    }
    int cnt = gend - gbase;
    bool lds = (cnt <= BCAP);
    __syncthreads();      // sm reuse barrier before lb init below
    lb[tid] = 0; lb[tid + 256] = 0;
    if (lds) {
        for (int i = tid; i < cnt; i += 256) stmp[i] = tmp[gbase + i];
    }
    __syncthreads();
    if (lds) {
        for (int i = tid; i < cnt; i += 256)
            atomicAdd(&lb[stmp[i] >> 17], 1);
    } else {
        for (int i = tid; i < cnt; i += 256)
            atomicAdd(&lb[tmp[gbase + i] >> 17], 1);
    }
    __syncthreads();
    int p = lb[2 * tid], q = lb[2 * tid + 1];
    int ps = p + q;
    sm[tid] = ps;
    __syncthreads();
    for (int off = 1; off < 256; off <<= 1) {
        int t = (tid >= off) ? sm[tid - off] : 0;
        __syncthreads();
        sm[tid] += t;
        __syncthreads();
    }
    int excl = sm[tid] - ps;
    int e0 = excl, e1 = excl + p;
    lo[2 * tid] = e0; lo[2 * tid + 1] = e1;
    int v0 = bk * 512 + 2 * tid;
    if (v0 <= n) row_ptr[v0] = gbase + e0;
    if (v0 + 1 <= n) row_ptr[v0 + 1] = gbase + e1;
    __syncthreads();
    if (lds) {
        for (int i = tid; i < cnt; i += 256) {
            unsigned v = stmp[i];
            int r = atomicAdd(&lo[v >> 17], 1);
            col[gbase + r] = (int)(v & 0x1FFFFu);
        }
    } else {
        for (int i = tid; i < cnt; i += 256) {
            unsigned v = tmp[gbase + i];
            int r = atomicAdd(&lo[v >> 17], 1);
            col[gbase + r] = (int)(v & 0x1FFFFu);
        }
    }
}

// ---------------------------------------------------------------------------
// Layer2 GEMM via MFMA bf16: [N,128(bf16-packed)]x[128,64].
__global__ __launch_bounds__(256) void gemm2_kernel(
        const unsigned* __restrict__ xp, const float* __restrict__ W,
        const float* __restrict__ att_s, const float* __restrict__ att_d,
        unsigned* __restrict__ hp, float* __restrict__ as_, float* __restrict__ ad_, int n) {
    __shared__ uint4 WtS[1024];                 // 16 KB: Wt[64ch][128k] bf16
    unsigned* Wt = (unsigned*)WtS;
    int tid = threadIdx.x;
    {   // stage W2^T
        int ch = tid & 63, fb = tid >> 6;
        #pragma unroll
        for (int j8 = 0; j8 < 4; ++j8) {
            int f0 = fb * 32 + j8 * 8;
            unsigned pk[4];
            #pragma unroll
            for (int p = 0; p < 4; ++p) {
                float lo = W[(size_t)(f0 + 2 * p) * 64 + ch];
                float hi = W[(size_t)(f0 + 2 * p + 1) * 64 + ch];
                pk[p] = f2bf(lo) | (f2bf(hi) << 16);
            }
            int bcol = (f0 * 2) ^ ((ch & 7) << 4);
            *(uint4*)&Wt[ch * 64 + (bcol >> 2)] = *(uint4*)pk;
        }
    }
    __syncthreads();
    int lane = tid & 63, w = tid >> 6;
    int col = lane & 15, quad = lane >> 4;
    int nodebase = blockIdx.x * 128 + w * 32;
    bf16x8 a[2][4];
    #pragma unroll
    for (int s = 0; s < 2; ++s) {
        int node = nodebase + s * 16 + col;
        bool v = node < n;
        #pragma unroll
        for (int kk = 0; kk < 4; ++kk) {
            uint4 u = v ? *(const uint4*)&xp[(size_t)node * 64 + kk * 16 + quad * 4]
                        : make_uint4(0, 0, 0, 0);
            a[s][kk] = *(bf16x8*)&u;
        }
    }
    f32x4 acc[2][4] = {};
    #pragma unroll
    for (int c = 0; c < 4; ++c) {
        int brow = c * 16 + col;
        bf16x8 b[4];
        #pragma unroll
        for (int kk = 0; kk < 4; ++kk) {
            int bcol = (kk * 64 + quad * 16) ^ ((brow & 7) << 4);
            b[kk] = *(bf16x8*)&Wt[brow * 64 + (bcol >> 2)];
        }
        #pragma unroll
        for (int s = 0; s < 2; ++s)
            #pragma unroll
            for (int kk = 0; kk < 4; ++kk)
                acc[s][c] = __builtin_amdgcn_mfma_f32_16x16x32_bf16(a[s][kk], b[kk], acc[s][c], 0, 0, 0);
    }
    float aS[4], aD[4];
    #pragma unroll
    for (int c = 0; c < 4; ++c) { aS[c] = att_s[c * 16 + col]; aD[c] = att_d[c * 16 + col]; }
    #pragma unroll
    for (int s = 0; s < 2; ++s) {
        #pragma unroll
        for (int c = 0; c < 4; ++c) {
            #pragma unroll
            for (int r = 0; r < 4; ++r) {
                float own = acc[s][c][r];
                float par = SWZ_F(own, 0x041F);
                int node = nodebase + s * 16 + quad * 4 + r;
                if (!(lane & 1) && node < n)
                    hp[(size_t)node * 32 + c * 8 + (col >> 1)] =
                        f2bf(own) | (f2bf(par) << 16);
            }
        }
        #pragma unroll
        for (int r = 0; r < 4; ++r) {
            float ps = 0.f, pd = 0.f;
            #pragma unroll
            for (int c = 0; c < 4; ++c) {
                ps = fmaf(acc[s][c][r], aS[c], ps);
                pd = fmaf(acc[s][c][r], aD[c], pd);
            }
            ps += SWZ_F(ps, 0x041F); pd += SWZ_F(pd, 0x041F);
            ps += SWZ_F(ps, 0x081F); pd += SWZ_F(pd, 0x081F);
            ps += SWZ_F(ps, 0x101F); pd += SWZ_F(pd, 0x101F);
            ps += SWZ_F(ps, 0x201F); pd += SWZ_F(pd, 0x201F);
            int node = nodebase + s * 16 + quad * 4 + r;
            if (col == 0 && node < n) { as_[node] = ps; ad_[node] = pd; }
        }
    }
}

// ---------------------------------------------------------------------------
// Aggregation layer1: wave per dst node, lane owns channels (2l, 2l+1).
#define A1_G8(B, K0) { \
    int t0 = SWZ_I(myc, (((B)+(K0)+0)<<5)); \
    int t1 = SWZ_I(myc, (((B)+(K0)+1)<<5)); \
    int t2 = SWZ_I(myc, (((B)+(K0)+2)<<5)); \
    int t3 = SWZ_I(myc, (((B)+(K0)+3)<<5)); \
    int t4 = SWZ_I(myc, (((B)+(K0)+4)<<5)); \
    int t5 = SWZ_I(myc, (((B)+(K0)+5)<<5)); \
    int t6 = SWZ_I(myc, (((B)+(K0)+6)<<5)); \
    int t7 = SWZ_I(myc, (((B)+(K0)+7)<<5)); \
    unsigned v0 = hp[(size_t)t0 * 64 + lane]; \
    unsigned v1 = hp[(size_t)t1 * 64 + lane]; \
    unsigned v2 = hp[(size_t)t2 * 64 + lane]; \
    unsigned v3 = hp[(size_t)t3 * 64 + lane]; \
    unsigned v4 = hp[(size_t)t4 * 64 + lane]; \
    unsigned v5 = hp[(size_t)t5 * 64 + lane]; \
    unsigned v6 = hp[(size_t)t6 * 64 + lane]; \
    unsigned v7 = hp[(size_t)t7 * 64 + lane]; \
    float q0 = SWZ_F(ew, ((((K0)+0)<<5)|0x10)); \
    float q1 = SWZ_F(ew, ((((K0)+1)<<5)|0x10)); \
    float q2 = SWZ_F(ew, ((((K0)+2)<<5)|0x10)); \
    float q3 = SWZ_F(ew, ((((K0)+3)<<5)|0x10)); \
    float q4 = SWZ_F(ew, ((((K0)+4)<<5)|0x10)); \
    float q5 = SWZ_F(ew, ((((K0)+5)<<5)|0x10)); \
    float q6 = SWZ_F(ew, ((((K0)+6)<<5)|0x10)); \
    float q7 = SWZ_F(ew, ((((K0)+7)<<5)|0x10)); \
    s += q0; acc0 = fmaf(q0, bflo(v0), acc0); acc1 = fmaf(q0, bfhi(v0), acc1); \
    s += q1; acc0 = fmaf(q1, bflo(v1), acc0); acc1 = fmaf(q1, bfhi(v1), acc1); \
    s += q2; acc0 = fmaf(q2, bflo(v2), acc0); acc1 = fmaf(q2, bfhi(v2), acc1); \
    s += q3; acc0 = fmaf(q3, bflo(v3), acc0); acc1 = fmaf(q3, bfhi(v3), acc1); \
    s += q4; acc0 = fmaf(q4, bflo(v4), acc0); acc1 = fmaf(q4, bfhi(v4), acc1); \
    s += q5; acc0 = fmaf(q5, bflo(v5), acc0); acc1 = fmaf(q5, bfhi(v5), acc1); \
    s += q6; acc0 = fmaf(q6, bflo(v6), acc0); acc1 = fmaf(q6, bfhi(v6), acc1); \
    s += q7; acc0 = fmaf(q7, bflo(v7), acc0); acc1 = fmaf(q7, bfhi(v7), acc1); }

#define A1_SUB(B) { \
    int sspec = SWZ_I(myc, (((B)<<5) | 0x0F)); \
    float ee_ = as_[(size_t)sspec * 4 + head] + adv; \
    ee_ = fmaxf(ee_, 0.2f * ee_); \
    float ew = ((cb + (B) + (lane & 15)) < end) ? __expf(ee_) : 0.f; \
    A1_G8(B, 0) \
    if (m > (B) + 8) A1_G8(B, 8) }

__global__ __launch_bounds__(256) void agg1_kernel(
        const unsigned* __restrict__ hp, const float* __restrict__ as_,
        const float* __restrict__ ad_, const int* __restrict__ row_ptr,
        const int* __restrict__ col, const float* __restrict__ bias,
        unsigned* __restrict__ outp, int n) {
    int wid = (blockIdx.x * 256 + threadIdx.x) >> 6;
    int lane = threadIdx.x & 63;
    if (wid >= n) return;
    int node = wid;
    int head = lane >> 4;
    float adv = ad_[(size_t)node * 4 + head];
    float e0 = as_[(size_t)node * 4 + head] + adv;
    e0 = fmaxf(e0, 0.2f * e0);
    float w0 = __expf(e0);
    float s = w0;
    unsigned u0 = hp[(size_t)node * 64 + lane];
    float acc0 = w0 * bflo(u0), acc1 = w0 * bfhi(u0);
    int beg = row_ptr[node], end = row_ptr[node + 1];
    for (int cb = beg; cb < end; cb += 32) {
        int m = end - cb; if (m > 32) m = 32;
        int ci = cb + (lane & 31);
        int myc = col[(ci < end) ? ci : (end - 1)];
        A1_SUB(0)
        if (m > 16) A1_SUB(16)
    }
    float inv = 1.0f / (s + 1e-16f);
    float2 b = *(const float2*)&bias[lane * 2];
    outp[(size_t)node * 64 + lane] =
        f2bf(acc0 * inv + b.x) | (f2bf(acc1 * inv + b.y) << 16);
}

// Aggregation layer2: wave per dst node; halves process even/odd edges.
#define A2_G4(K0) { \
    int t0 = SWZ_I(myc, (((K0)+0)<<5)); \
    int t1 = SWZ_I(myc, (((K0)+1)<<5)); \
    int t2 = SWZ_I(myc, (((K0)+2)<<5)); \
    int t3 = SWZ_I(myc, (((K0)+3)<<5)); \
    unsigned v0 = hp[(size_t)t0 * 32 + wrd]; \
    unsigned v1 = hp[(size_t)t1 * 32 + wrd]; \
    unsigned v2 = hp[(size_t)t2 * 32 + wrd]; \
    unsigned v3 = hp[(size_t)t3 * 32 + wrd]; \
    float q0 = SWZ_F(ew, (((K0)+0)<<5)); \
    float q1 = SWZ_F(ew, (((K0)+1)<<5)); \
    float q2 = SWZ_F(ew, (((K0)+2)<<5)); \
    float q3 = SWZ_F(ew, (((K0)+3)<<5)); \
    s += q0; acc0 = fmaf(q0, bflo(v0), acc0); acc1 = fmaf(q0, bfhi(v0), acc1); \
    s += q1; acc0 = fmaf(q1, bflo(v1), acc0); acc1 = fmaf(q1, bfhi(v1), acc1); \
    s += q2; acc0 = fmaf(q2, bflo(v2), acc0); acc1 = fmaf(q2, bfhi(v2), acc1); \
    s += q3; acc0 = fmaf(q3, bflo(v3), acc0); acc1 = fmaf(q3, bfhi(v3), acc1); }

__global__ __launch_bounds__(256) void agg2_kernel(
        const unsigned* __restrict__ hp, const float* __restrict__ as_,
        const float* __restrict__ ad_, const int* __restrict__ row_ptr,
        const int* __restrict__ col, const float* __restrict__ bias,
        float* __restrict__ out, int n) {
    int wid = (blockIdx.x * 256 + threadIdx.x) >> 6;
    int lane = threadIdx.x & 63;
    if (wid >= n) return;
    int node = wid;
    int half = lane >> 5, wrd = lane & 31;
    float adv = ad_[node];
    float s = 0.f, acc0 = 0.f, acc1 = 0.f;
    {
        float e = as_[node] + adv; e = fmaxf(e, 0.2f * e);
        float w = __expf(e);
        if (half == 0) {
            unsigned u = hp[(size_t)node * 32 + wrd];
            s = w; acc0 = w * bflo(u); acc1 = w * bfhi(u);
        }
    }
    int beg = row_ptr[node], end = row_ptr[node + 1];
    for (int cb = beg; cb < end; cb += 64) {
        int m = end - cb; if (m > 64) m = 64;
        int idx = cb + 2 * (lane & 31) + half;
        int myc = col[(idx < end) ? idx : (end - 1)];
        float ee = as_[myc] + adv; ee = fmaxf(ee, 0.2f * ee);
        float ew = (idx < end) ? __expf(ee) : 0.f;
        A2_G4(0)
        if (m > 8)  A2_G4(4)
        if (m > 16) A2_G4(8)
        if (m > 24) A2_G4(12)
        if (m > 32) {
            A2_G4(16)
            if (m > 40) A2_G4(20)
            if (m > 48) A2_G4(24)
            if (m > 56) A2_G4(28)
        }
    }
    s += __shfl_xor(s, 32);
    acc0 += __shfl_xor(acc0, 32);
    acc1 += __shfl_xor(acc1, 32);
    if (half == 0) {
        float inv = 1.0f / (s + 1e-16f);
        float2 b = *(const float2*)&bias[wrd * 2];
        *(float2*)&out[(size_t)node * 64 + wrd * 2] =
            make_float2(acc0 * inv + b.x, acc1 * inv + b.y);
    }
}

// ---------------------------------------------------------------------------
extern "C" void kernel_launch(void* const* d_in, const int* in_sizes, int n_in,
                              void* d_out, int out_size, void* d_ws, size_t ws_size,
                              hipStream_t stream) {
    const float* inp   = (const float*)d_in[0];
    const int*   ei    = (const int*)d_in[1];
    const float* W1    = (const float*)d_in[2];
    const float* atts1 = (const float*)d_in[3];
    const float* attd1 = (const float*)d_in[4];
    const float* bias1 = (const float*)d_in[5];
    const float* W2    = (const float*)d_in[6];
    const float* atts2 = (const float*)d_in[7];
    const float* attd2 = (const float*)d_in[8];
    const float* bias2 = (const float*)d_in[9];
    float* out = (float*)d_out;

    const int N = N_NODES;
    const int E = in_sizes[1] / 2;

    const int EB = (E + 2047) / 2048;          // edge blocks
    const int K = 256 * EB;                    // ghBM length
    const int nbK = (K + SCAN_BLOCK - 1) / SCAN_BLOCK;   // <=256 for E<=2M
    const int nG1 = (N + 127) / 128;           // gemm1 blocks

    unsigned* h1p = (unsigned*)d_ws;               // N*64 uints (layer2 reuses N*32)
    unsigned* x1p = h1p + (size_t)N * 64;          // N*64 uints (bf16-packed x1)
    float* as1 = (float*)(x1p + (size_t)N * 64);   // N*4
    float* ad1 = as1 + (size_t)N * 4;              // N*4
    int* row_ptr  = (int*)(ad1 + (size_t)N * 4);   // N+1
    int* col      = row_ptr + N + 1;               // E
    int* ghBM     = col + E;                       // 256*EB
    int* bsum     = ghBM + K;                      // 256
    unsigned* tmp = x1p;                           // E uints, aliases x1p (dead until agg1)

    // CSR build (hist fused with layer1 GEMM; scan finalized in consumers)
    histgemm1_kernel<<<EB + nG1, 256, 0, stream>>>(
        ei, ghBM, EB, E, inp, W1, atts1, attd1, h1p, as1, ad1, N);
    pscanA_kernel<<<nbK, SCAN_BLOCK, 0, stream>>>(ghBM, bsum, K);
    scatterB_kernel<<<EB, 256, 0, stream>>>(ei, ghBM, EB, bsum, nbK, tmp, E);
    bucketC_kernel<<<256, 256, 0, stream>>>(tmp, ghBM, EB, bsum, nbK, row_ptr, col, E, N);

    agg1_kernel<<<(N + 3) / 4, 256, 0, stream>>>(h1p, as1, ad1, row_ptr, col, bias1, x1p, N);

    // layer 2 (h2p aliases h1p; as2/ad2 alias as1/ad1)
    gemm2_kernel<<<(N + 127) / 128, 256, 0, stream>>>(x1p, W2, atts2, attd2, h1p, as1, ad1, N);
    agg2_kernel<<<(N + 3) / 4, 256, 0, stream>>>(h1p, as1, ad1, row_ptr, col, bias2, out, N);
}